// Round 8
// baseline (528.033 us; speedup 1.0000x reference)
//
#include <hip/hip_runtime.h>
#include <math.h>

#define BB 32
#define DD 64
#define LL 8192
#define KK 512
#define NN (BB*LL)                 // 262144 rows

#define OUT0_SZ  (BB*DD*LL)        // 16777216
#define LOSS_OFF (OUT0_SZ)
#define PERP_OFF (OUT0_SZ + 1)
#define W_OFF    (OUT0_SZ + 2)
#define IDX_OFF  (W_OFF + KK*DD)   // 16809986

// ws float-offsets: tvec[512] | hist[512] | lacc | pad | wpack_h (32768 u16) | wpack_l
#define WS_TVEC 0
#define WS_HIST 512
#define WS_LACC 1024
#define WS_WPH  1032
#define WS_WPL  (1032 + 16384)
// needs ws_size >= ~135 KB (verified available R2-R6)

typedef __attribute__((ext_vector_type(4))) float f32x4;
typedef __attribute__((ext_vector_type(8))) short s16x8;
typedef unsigned long long u64;

// 2-term filter error: |2*sum(dx*w)| <= ~1e-4 at 6sigma + chain wobble ~1e-5.
// Window 5e-4 = ~2.5x the 2-sided bound. d2/marker completeness machinery
// (verified R2/R4/R5/R6) unchanged.
#define WINDOW 5e-4f

__device__ __forceinline__ unsigned short f2bf(float f) {   // RNE f32->bf16
  unsigned int u = __float_as_uint(f);
  return (unsigned short)((u + 0x7FFFu + ((u >> 16) & 1u)) >> 16);
}
__device__ __forceinline__ float bf2f(unsigned short s) {
  return __uint_as_float(((unsigned int)s) << 16);
}
__device__ __forceinline__ u64 shflx64(u64 v, int m) {
  unsigned lo = __shfl_xor((unsigned)v, m);
  unsigned hi = __shfl_xor((unsigned)(v >> 32), m);
  return ((u64)hi << 32) | lo;
}
// order-preserving float<->uint (handles negative d' = t - 2g)
__device__ __forceinline__ unsigned fenc(float f) {
  unsigned u = __float_as_uint(f);
  return (u & 0x80000000u) ? ~u : (u | 0x80000000u);
}
__device__ __forceinline__ float fdec(unsigned e) {
  return __uint_as_float((e & 0x80000000u) ? (e ^ 0x80000000u) : ~e);
}

// -----------------------------------------------------------------------------
// init (32768 threads): exact t_k (np-pairwise), zero hist/lacc, pack codebook
// bf16 hi/lo in MFMA B-fragment order (verified R2-R6), w passthrough.
__global__ void vq_init(const float* __restrict__ w, float* __restrict__ ws,
                        float* __restrict__ dout) {
#pragma clang fp contract(off)
  int t = blockIdx.x * blockDim.x + threadIdx.x;
  if (t < KK) {
    const float* wr = w + t * DD;
    float r[8];
#pragma unroll
    for (int j = 0; j < 8; j++) { float v = wr[j]; r[j] = v * v; }
#pragma unroll
    for (int blk = 8; blk < 64; blk += 8) {
#pragma unroll
      for (int j = 0; j < 8; j++) { float v = wr[blk + j]; float a = v * v; r[j] = r[j] + a; }
    }
    ws[WS_TVEC + t] = ((r[0] + r[1]) + (r[2] + r[3])) + ((r[4] + r[5]) + (r[6] + r[7]));
    ((int*)ws)[WS_HIST + t] = 0;
  }
  if (t == 0) ws[WS_LACC] = 0.0f;

  // codebook pack: B elem (k,n) -> lane = n + 16*(k/8), j = k%8
  {
    int j    = t & 7;
    int lane = (t >> 3) & 63;
    int ks   = (t >> 9) & 1;
    int ct   = t >> 10;
    int code = ct * 16 + (lane & 15);
    int d    = ks * 32 + ((lane >> 4) << 3) + j;
    float v  = w[code * DD + d];
    unsigned short h = f2bf(v);
    unsigned short l = f2bf(v - bf2f(h));
    ((unsigned short*)(ws + WS_WPH))[((ct * 2 + ks) * 64 + lane) * 8 + j] = h;
    ((unsigned short*)(ws + WS_WPL))[((ct * 2 + ks) * 64 + lane) * 8 + j] = l;
  }

  // weight passthrough (W_OFF 8B-aligned -> float2)
  if (t < KK * DD / 2) {
    ((float2*)(dout + W_OFF))[t] = ((const float2*)w)[t];
  }
}

// -----------------------------------------------------------------------------
// main: 1024 blocks x 256 threads. Wave owns 64 rows (4 MFMA row-tiles), lane
// owns 1 row. 2-TERM filter: xh.(wh+wl) -> only hi A-fragments (one staging
// pass, -32 VGPR, 16 MFMA/ct). x never held across the loop (epilogue/rescue
// stream it from L3). Register budget targets 3 waves/SIMD.
__launch_bounds__(256, 3)
__global__ void vq_main(const float* __restrict__ x, const float* __restrict__ w,
                        const float* __restrict__ ws, float* __restrict__ dout) {
#pragma clang fp contract(off)
  __shared__ uint4 xs_lds[4][64][8];        // 32 KB, bf16-hi staged, swizzled
  __shared__ float t_lds[KK];               // 2 KB
  __shared__ u64   g_lds[256];              // 2 KB
  __shared__ unsigned short cand[256][4];   // 2 KB
  __shared__ int   ccnt[256];               // 1 KB
  __shared__ unsigned char flags[KK];       // 512 B

  const float* tvec = ws + WS_TVEC;
  const s16x8* wph8 = (const s16x8*)(ws + WS_WPH);
  const s16x8* wpl8 = (const s16x8*)(ws + WS_WPL);
  int* hist = (int*)ws + WS_HIST;
  float* lacc = (float*)ws + WS_LACC;

  const int tid  = threadIdx.x;
  const int lane = tid & 63;
  const int wv   = tid >> 6;
  const int res  = lane & 15;       // code residue this lane tracks

  for (int e = tid; e < KK; e += 256) { t_lds[e] = tvec[e]; flags[e] = 0; }
  ccnt[tid] = 0;

  const int n = blockIdx.x * 256 + wv * 64 + lane;   // lane's row
  const int b = n >> 13, l = n & 8191;
  const float* px = x + (size_t)b * DD * LL + l;

  // ---- stage bf16-hi into LDS (single pass; xv transient) ----
  {
    float xv[64];
#pragma unroll
    for (int i = 0; i < 64; i++) xv[i] = px[(size_t)i * LL];
#pragma unroll
    for (int blk = 0; blk < 8; blk++) {
      unsigned ph[4];
#pragma unroll
      for (int q = 0; q < 4; q++) {
        float v0 = xv[blk * 8 + 2 * q], v1 = xv[blk * 8 + 2 * q + 1];
        ph[q] = (unsigned)f2bf(v0) | ((unsigned)f2bf(v1) << 16);
      }
      int sw = blk ^ (lane & 7);          // swizzle (verified: b128-floor conflicts)
      uint4 vh; vh.x = ph[0]; vh.y = ph[1]; vh.z = ph[2]; vh.w = ph[3];
      xs_lds[wv][lane][sw] = vh;
    }
  }
  __syncthreads();   // barrier #1: t_lds/flags/ccnt + staging visible

  // A-fragments (verified mapping): row = t2*16+(lane&15), k = ks*32+8*(lane>>4)+j
  s16x8 afh[4][2];
  {
    const s16x8* xs8 = (const s16x8*)xs_lds;
#pragma unroll
    for (int t2 = 0; t2 < 4; t2++)
#pragma unroll
      for (int ks = 0; ks < 2; ks++) {
        int idx = (wv * 64 + t2 * 16 + (lane & 15)) * 8 + ((ks * 4 + (lane >> 4)) ^ (lane & 7));
        afh[t2][ks] = xs8[idx];
      }
  }

  float d1[4][4], d2[4][4]; int k1[4][4];
#pragma unroll
  for (int t2 = 0; t2 < 4; t2++)
#pragma unroll
    for (int r = 0; r < 4; r++) { d1[t2][r] = INFINITY; d2[t2][r] = INFINITY; k1[t2][r] = 0; }

  // B prefetch (1-deep ring)
  s16x8 bh0 = wph8[lane], bh1 = wph8[64 + lane];
  s16x8 bl0 = wpl8[lane], bl1 = wpl8[64 + lane];
  float tc = t_lds[res];

#pragma clang loop unroll(disable)
  for (int ct = 0; ct < 32; ct++) {
    int cn = (ct + 1) & 31;   // wrap: harmless re-read
    s16x8 nh0 = wph8[cn * 128 + lane],      nh1 = wph8[cn * 128 + 64 + lane];
    s16x8 nl0 = wpl8[cn * 128 + lane],      nl1 = wpl8[cn * 128 + 64 + lane];
    float ntc = t_lds[cn * 16 + res];

#pragma unroll
    for (int t2 = 0; t2 < 4; t2++) {
      f32x4 acc = {0.f, 0.f, 0.f, 0.f};
      acc = __builtin_amdgcn_mfma_f32_16x16x32_bf16(afh[t2][0], bl0, acc, 0, 0, 0);
      acc = __builtin_amdgcn_mfma_f32_16x16x32_bf16(afh[t2][1], bl1, acc, 0, 0, 0);
      acc = __builtin_amdgcn_mfma_f32_16x16x32_bf16(afh[t2][0], bh0, acc, 0, 0, 0);
      acc = __builtin_amdgcn_mfma_f32_16x16x32_bf16(afh[t2][1], bh1, acc, 0, 0, 0);
#pragma unroll
      for (int r = 0; r < 4; r++) {
        float dap = fmaf(-2.0f, acc[r], tc);   // s-less: d' = t - 2g
        // best-2 via min/max (6 VALU): d2 = min(d2, max(d1,dap)); d1 = min(d1,dap)
        float m  = fmaxf(d1[t2][r], dap);
        d2[t2][r] = fminf(d2[t2][r], m);
        bool c1 = dap < d1[t2][r];
        k1[t2][r] = c1 ? ct : k1[t2][r];
        d1[t2][r] = fminf(d1[t2][r], dap);
      }
    }
    bh0 = nh0; bh1 = nh1; bl0 = nl0; bl1 = nl1; tc = ntc;
  }

  // ---- per-row global min (order-preserving encode handles negative d') ----
  u64 gmin[4][4];
#pragma unroll
  for (int t2 = 0; t2 < 4; t2++)
#pragma unroll
    for (int r = 0; r < 4; r++) {
      u64 pk = (((u64)fenc(d1[t2][r])) << 32) | (u64)(k1[t2][r] * 16 + res);
      u64 q1 = shflx64(pk, 1); pk = pk < q1 ? pk : q1;
      u64 q2 = shflx64(pk, 2); pk = pk < q2 ? pk : q2;
      u64 q4 = shflx64(pk, 4); pk = pk < q4 ? pk : q4;
      u64 q8 = shflx64(pk, 8); pk = pk < q8 ? pk : q8;
      gmin[t2][r] = pk;
    }

  // window collection (rows wave-owned; LDS atomics)
#pragma unroll
  for (int t2 = 0; t2 < 4; t2++)
#pragma unroll
    for (int r = 0; r < 4; r++) {
      int row = wv * 64 + t2 * 16 + ((lane >> 4) << 2) + r;
      if (res == 0) g_lds[row] = gmin[t2][r];
      float thr = fdec((unsigned)(gmin[t2][r] >> 32)) + WINDOW;
      bool in1 = d1[t2][r] <= thr;
      bool in2 = d2[t2][r] <= thr;
      if (in1) { int p = atomicAdd(&ccnt[row], 1); if (p < 4) cand[row][p] = (unsigned short)(k1[t2][r] * 16 + res); }
      if (in2) { int p = atomicAdd(&ccnt[row], 1); if (p < 4) cand[row][p] = (unsigned short)(512 + res); }
    }
  __syncthreads();   // barrier #2: collection visible

  // ---- owner decision (every lane owns its row); x streamed from L3 ----
  int kwin;
  {
    int row = wv * 64 + lane;
    int cnt = ccnt[row];
    if (cnt <= 1) {
      kwin = (int)(g_lds[row] & 0x1FFu);
    } else {
      // exact rescue: bit-identical chains to reference (x loaded fresh)
      float xr[64];
#pragma unroll
      for (int i = 0; i < 64; i++) xr[i] = px[(size_t)i * LL];
      float s;
      {
        float r[8];
#pragma unroll
        for (int j = 0; j < 8; j++) r[j] = xr[j] * xr[j];
#pragma unroll
        for (int blk = 8; blk < 64; blk += 8)
#pragma unroll
          for (int j = 0; j < 8; j++) { float a = xr[blk + j] * xr[blk + j]; r[j] = r[j] + a; }
        s = ((r[0] + r[1]) + (r[2] + r[3])) + ((r[4] + r[5]) + (r[6] + r[7]));
      }
      u64 best = ~0ULL;
      auto evalExact = [&](int c) {
        const float4* wr = (const float4*)(w + c * DD);
        float gg = 0.0f;
#pragma unroll
        for (int i = 0; i < 16; i++) {
          float4 wq = wr[i];
          gg = fmaf(xr[4 * i + 0], wq.x, gg); gg = fmaf(xr[4 * i + 1], wq.y, gg);
          gg = fmaf(xr[4 * i + 2], wq.z, gg); gg = fmaf(xr[4 * i + 3], wq.w, gg);
        }
        float de = fmaf(-2.0f, gg, s + t_lds[c]);   // ref chain: fl(s+t) then fma
        u64 pk = (((u64)__float_as_uint(de)) << 32) | (u64)c;   // de>0: bit order ok
        if (pk < best) best = pk;
      };
      if (cnt > 4) {
        for (int c = 0; c < KK; c++) evalExact(c);
      } else {
        for (int i = 0; i < cnt; i++) {
          int c = cand[row][i];
          if (c < 512) evalExact(c);
          else { int c0 = c - 512; for (int jj = 0; jj < 32; jj++) evalExact(jj * 16 + c0); }
        }
      }
      kwin = (int)(best & 0x1FFu);   // masked: logic bug => wrong answer, never OOB
    }
  }

  // ---- epilogue: quantized output (transposed back), loss partial, idx, flags ----
  // x streamed directly (L3-hot); short live ranges, no 64-reg block.
  float ls = 0.0f;
  {
    float* o = dout + (size_t)b * DD * LL + l;
    const float4* wr = (const float4*)(w + kwin * DD);
#pragma unroll
    for (int i = 0; i < 16; i++) {
      float4 v = wr[i];
      float xa = px[(size_t)(4 * i + 0) * LL];
      float xb = px[(size_t)(4 * i + 1) * LL];
      float xc = px[(size_t)(4 * i + 2) * LL];
      float xd = px[(size_t)(4 * i + 3) * LL];
      o[(size_t)(4 * i + 0) * LL] = v.x; o[(size_t)(4 * i + 1) * LL] = v.y;
      o[(size_t)(4 * i + 2) * LL] = v.z; o[(size_t)(4 * i + 3) * LL] = v.w;
      float df;
      df = v.x - xa; ls = fmaf(df, df, ls);
      df = v.y - xb; ls = fmaf(df, df, ls);
      df = v.z - xc; ls = fmaf(df, df, ls);
      df = v.w - xd; ls = fmaf(df, df, ls);
    }
  }
  dout[IDX_OFF + n] = (float)kwin;
  flags[kwin] = 1;   // byte races benign (same value)

  // loss: wave reduce then one atomic per wave (order-insensitive at tolerance)
#pragma unroll
  for (int o = 32; o > 0; o >>= 1) ls += __shfl_down(ls, o);
  if ((tid & 63) == 0) atomicAdd(lacc, ls);

  __syncthreads();   // barrier #3: flags complete
  for (int e = tid; e < KK; e += 256)
    if (flags[e]) atomicOr(&hist[e], 1);
}

// -----------------------------------------------------------------------------
// final: perplexity count + loss scalar (w passthrough in vq_init)
__global__ void vq_final(const float* __restrict__ ws, float* __restrict__ dout) {
  __shared__ int red[512];
  const int* hist = (const int*)ws + WS_HIST;
  int tid = threadIdx.x;
  red[tid] = (hist[tid] != 0) ? 1 : 0;
  __syncthreads();
  for (int sx = 256; sx > 0; sx >>= 1) {
    if (tid < sx) red[tid] += red[tid + sx];
    __syncthreads();
  }
  if (tid == 0) {
    dout[PERP_OFF] = (float)red[0];
    float m = ws[WS_LACC] / 16777216.0f;
    dout[LOSS_OFF] = m + 0.1f * m;   // q + 0.1*e with q==e numerically
  }
}

extern "C" void kernel_launch(void* const* d_in, const int* in_sizes, int n_in,
                              void* d_out, int out_size, void* d_ws, size_t ws_size,
                              hipStream_t stream) {
  const float* x = (const float*)d_in[0];
  const float* w = (const float*)d_in[1];
  float* dout = (float*)d_out;
  float* ws = (float*)d_ws;

  vq_init<<<128, 256, 0, stream>>>(w, ws, dout);
  vq_main<<<NN / 256, 256, 0, stream>>>(x, w, ws, dout);
  vq_final<<<1, 512, 0, stream>>>(ws, dout);
}

// Round 9
// 337.913 us; speedup vs baseline: 1.5626x; 1.5626x over previous
//
#include <hip/hip_runtime.h>
#include <math.h>

#define BB 32
#define DD 64
#define LL 8192
#define KK 512
#define NN (BB*LL)                 // 262144 rows

#define OUT0_SZ  (BB*DD*LL)        // 16777216
#define LOSS_OFF (OUT0_SZ)
#define PERP_OFF (OUT0_SZ + 1)
#define W_OFF    (OUT0_SZ + 2)
#define IDX_OFF  (W_OFF + KK*DD)   // 16809986

// ws float-offsets: tvec[512] | hist[512] | lacc | ctr | pad | wpack_h | wpack_l
#define WS_TVEC 0
#define WS_HIST 512
#define WS_LACC 1024
#define WS_CTR  1025
#define WS_WPH  1032
#define WS_WPL  (1032 + 16384)
// needs ws_size >= ~135 KB (verified available R2-R7)

typedef __attribute__((ext_vector_type(4))) float f32x4;
typedef __attribute__((ext_vector_type(8))) short s16x8;
typedef unsigned long long u64;

#define WINDOW 1e-4f   // R6-verified: apx err ~1e-5 + ref wobble ~8e-6 + quant 1.5e-5, 3x margin
#define DBIAS  4.0f    // uniform +4 shift -> d' in [3.6,4.4], positive => as_uint monotone

__device__ __forceinline__ unsigned short f2bf(float f) {   // RNE f32->bf16
  unsigned int u = __float_as_uint(f);
  return (unsigned short)((u + 0x7FFFu + ((u >> 16) & 1u)) >> 16);
}
__device__ __forceinline__ float bf2f(unsigned short s) {
  return __uint_as_float(((unsigned int)s) << 16);
}
__device__ __forceinline__ u64 shflx64(u64 v, int m) {
  unsigned lo = __shfl_xor((unsigned)v, m);
  unsigned hi = __shfl_xor((unsigned)(v >> 32), m);
  return ((u64)hi << 32) | lo;
}

// -----------------------------------------------------------------------------
// init (32768 threads): exact t_k (np-pairwise), zero hist/lacc/ctr, pack
// codebook bf16 hi/lo in MFMA B-fragment order (verified R2-R6), w passthrough.
__global__ void vq_init(const float* __restrict__ w, float* __restrict__ ws,
                        float* __restrict__ dout) {
#pragma clang fp contract(off)
  int t = blockIdx.x * blockDim.x + threadIdx.x;
  if (t < KK) {
    const float* wr = w + t * DD;
    float r[8];
#pragma unroll
    for (int j = 0; j < 8; j++) { float v = wr[j]; r[j] = v * v; }
#pragma unroll
    for (int blk = 8; blk < 64; blk += 8) {
#pragma unroll
      for (int j = 0; j < 8; j++) { float v = wr[blk + j]; float a = v * v; r[j] = r[j] + a; }
    }
    ws[WS_TVEC + t] = ((r[0] + r[1]) + (r[2] + r[3])) + ((r[4] + r[5]) + (r[6] + r[7]));
    ((int*)ws)[WS_HIST + t] = 0;
  }
  if (t == 0) { ws[WS_LACC] = 0.0f; ((int*)ws)[WS_CTR] = 0; }

  // codebook pack: B elem (k,n) -> lane = n + 16*(k/8), j = k%8
  {
    int j    = t & 7;
    int lane = (t >> 3) & 63;
    int ks   = (t >> 9) & 1;
    int ct   = t >> 10;
    int code = ct * 16 + (lane & 15);
    int d    = ks * 32 + ((lane >> 4) << 3) + j;
    float v  = w[code * DD + d];
    unsigned short h = f2bf(v);
    unsigned short l = f2bf(v - bf2f(h));
    ((unsigned short*)(ws + WS_WPH))[((ct * 2 + ks) * 64 + lane) * 8 + j] = h;
    ((unsigned short*)(ws + WS_WPL))[((ct * 2 + ks) * 64 + lane) * 8 + j] = l;
  }

  // weight passthrough (W_OFF 8B-aligned -> float2)
  if (t < KK * DD / 2) {
    ((float2*)(dout + W_OFF))[t] = ((const float2*)w)[t];
  }
}

// -----------------------------------------------------------------------------
// main: 1024 blocks x 256 threads. Wave owns 64 rows (4 MFMA row-tiles), lane
// owns 1 row. R6-verified 3-term filter; NEW: biased-positive packed-u32
// best-2 insert (5 VALU/acc) and last-block-merged final (one fewer launch).
__launch_bounds__(256, 2)
__global__ void vq_main(const float* __restrict__ x, const float* __restrict__ w,
                        const float* __restrict__ ws, float* __restrict__ dout) {
#pragma clang fp contract(off)
  __shared__ uint4 xs_lds[4][64][8];        // 32 KB, holds hi then lo (time-muxed)
  __shared__ float t_lds[KK];               // 2 KB
  __shared__ u64   g_lds[256];              // 2 KB
  __shared__ unsigned short cand[256][4];   // 1 KB
  __shared__ int   ccnt[256];               // 1 KB
  __shared__ unsigned char flags[KK];       // 512 B
  __shared__ int   lastblk;

  const float* tvec = ws + WS_TVEC;
  const s16x8* wph8 = (const s16x8*)(ws + WS_WPH);
  const s16x8* wpl8 = (const s16x8*)(ws + WS_WPL);
  int* hist = (int*)ws + WS_HIST;
  float* lacc = (float*)ws + WS_LACC;
  int* ctr = (int*)ws + WS_CTR;

  const int tid  = threadIdx.x;
  const int lane = tid & 63;
  const int wv   = tid >> 6;
  const int res  = lane & 15;       // code residue this lane tracks

  for (int e = tid; e < KK; e += 256) { t_lds[e] = tvec[e]; flags[e] = 0; }
  ccnt[tid] = 0;

  const int n = blockIdx.x * 256 + wv * 64 + lane;   // lane's row
  const int b = n >> 13, l = n & 8191;
  const float* px = x + (size_t)b * DD * LL + l;

  // ---- stage: hi pass, read afh; lo pass, read afl (one 32 KB buffer) ----
  s16x8 afh[4][2], afl[4][2];
  {
    float xv[64];
#pragma unroll
    for (int i = 0; i < 64; i++) xv[i] = px[(size_t)i * LL];

    // hi pass
#pragma unroll
    for (int blk = 0; blk < 8; blk++) {
      unsigned ph[4];
#pragma unroll
      for (int q = 0; q < 4; q++) {
        float v0 = xv[blk * 8 + 2 * q], v1 = xv[blk * 8 + 2 * q + 1];
        ph[q] = (unsigned)f2bf(v0) | ((unsigned)f2bf(v1) << 16);
      }
      int sw = blk ^ (lane & 7);          // swizzle (verified: b128-floor conflicts)
      uint4 vh; vh.x = ph[0]; vh.y = ph[1]; vh.z = ph[2]; vh.w = ph[3];
      xs_lds[wv][lane][sw] = vh;
    }
    __syncthreads();   // barrier #1: t_lds/flags/ccnt + hi stage visible
    {
      const s16x8* xs8 = (const s16x8*)xs_lds;
#pragma unroll
      for (int t2 = 0; t2 < 4; t2++)
#pragma unroll
        for (int ks = 0; ks < 2; ks++) {
          int idx = (wv * 64 + t2 * 16 + (lane & 15)) * 8 + ((ks * 4 + (lane >> 4)) ^ (lane & 7));
          afh[t2][ks] = xs8[idx];
        }
    }
    __syncthreads();   // barrier #2: hi reads complete before lo overwrite

    // lo pass (residuals), same buffer
#pragma unroll
    for (int blk = 0; blk < 8; blk++) {
      unsigned pl[4];
#pragma unroll
      for (int q = 0; q < 4; q++) {
        float v0 = xv[blk * 8 + 2 * q],     h0f = bf2f(f2bf(v0));
        float v1 = xv[blk * 8 + 2 * q + 1], h1f = bf2f(f2bf(v1));
        pl[q] = (unsigned)f2bf(v0 - h0f) | ((unsigned)f2bf(v1 - h1f) << 16);
      }
      int sw = blk ^ (lane & 7);
      uint4 vl; vl.x = pl[0]; vl.y = pl[1]; vl.z = pl[2]; vl.w = pl[3];
      xs_lds[wv][lane][sw] = vl;
    }
    __syncthreads();   // barrier #3: lo staged
    {
      const s16x8* xs8 = (const s16x8*)xs_lds;
#pragma unroll
      for (int t2 = 0; t2 < 4; t2++)
#pragma unroll
        for (int ks = 0; ks < 2; ks++) {
          int idx = (wv * 64 + t2 * 16 + (lane & 15)) * 8 + ((ks * 4 + (lane >> 4)) ^ (lane & 7));
          afl[t2][ks] = xs8[idx];
        }
    }
  }   // xv dead here

  // packed (quantized-d | ct) best-2 state
  unsigned pk1[4][4], pk2[4][4];
#pragma unroll
  for (int t2 = 0; t2 < 4; t2++)
#pragma unroll
    for (int r = 0; r < 4; r++) { pk1[t2][r] = 0xFFFFFFFFu; pk2[t2][r] = 0xFFFFFFFFu; }
  const unsigned MASKQ = 0xFFFFFFE0u;

  // B prefetch (1-deep ring)
  s16x8 bh0 = wph8[lane], bh1 = wph8[64 + lane];
  s16x8 bl0 = wpl8[lane], bl1 = wpl8[64 + lane];
  float tcb = t_lds[res] + DBIAS;

#pragma clang loop unroll(disable)
  for (int ct = 0; ct < 32; ct++) {
    int cn = (ct + 1) & 31;   // wrap: harmless re-read
    s16x8 nh0 = wph8[cn * 128 + lane],      nh1 = wph8[cn * 128 + 64 + lane];
    s16x8 nl0 = wpl8[cn * 128 + lane],      nl1 = wpl8[cn * 128 + 64 + lane];
    float ntcb = t_lds[cn * 16 + res] + DBIAS;

#pragma unroll
    for (int t2 = 0; t2 < 4; t2++) {
      f32x4 acc = {0.f, 0.f, 0.f, 0.f};
      acc = __builtin_amdgcn_mfma_f32_16x16x32_bf16(afl[t2][0], bh0, acc, 0, 0, 0);
      acc = __builtin_amdgcn_mfma_f32_16x16x32_bf16(afl[t2][1], bh1, acc, 0, 0, 0);
      acc = __builtin_amdgcn_mfma_f32_16x16x32_bf16(afh[t2][0], bl0, acc, 0, 0, 0);
      acc = __builtin_amdgcn_mfma_f32_16x16x32_bf16(afh[t2][1], bl1, acc, 0, 0, 0);
      acc = __builtin_amdgcn_mfma_f32_16x16x32_bf16(afh[t2][0], bh0, acc, 0, 0, 0);
      acc = __builtin_amdgcn_mfma_f32_16x16x32_bf16(afh[t2][1], bh1, acc, 0, 0, 0);
#pragma unroll
      for (int r = 0; r < 4; r++) {
        float dap = fmaf(-2.0f, acc[r], tcb);            // biased d' > 0
        unsigned pkd = (__float_as_uint(dap) & MASKQ) | (unsigned)ct;
        unsigned mx = pk1[t2][r] > pkd ? pk1[t2][r] : pkd;   // v_max_u32
        pk2[t2][r] = pk2[t2][r] < mx ? pk2[t2][r] : mx;      // v_min_u32
        pk1[t2][r] = pk1[t2][r] < pkd ? pk1[t2][r] : pkd;    // v_min_u32
      }
    }
    bh0 = nh0; bh1 = nh1; bl0 = nl0; bl1 = nl1; tcb = ntcb;
  }

  // ---- per-row global min (u64 butterfly over the 16 residue lanes) ----
  u64 gmin[4][4];
#pragma unroll
  for (int t2 = 0; t2 < 4; t2++)
#pragma unroll
    for (int r = 0; r < 4; r++) {
      unsigned k9 = ((pk1[t2][r] & 31u) << 4) | (unsigned)res;
      u64 pk = (((u64)(pk1[t2][r] & MASKQ)) << 32) | (u64)k9;
      u64 q1 = shflx64(pk, 1); pk = pk < q1 ? pk : q1;
      u64 q2 = shflx64(pk, 2); pk = pk < q2 ? pk : q2;
      u64 q4 = shflx64(pk, 4); pk = pk < q4 ? pk : q4;
      u64 q8 = shflx64(pk, 8); pk = pk < q8 ? pk : q8;
      gmin[t2][r] = pk;
    }

  // window collection (rows wave-owned; LDS atomics). Quantization (32 ulp(4)
  // ~1.5e-5, floor-consistent) is inside WINDOW's margin.
#pragma unroll
  for (int t2 = 0; t2 < 4; t2++)
#pragma unroll
    for (int r = 0; r < 4; r++) {
      int row = wv * 64 + t2 * 16 + ((lane >> 4) << 2) + r;
      if (res == 0) g_lds[row] = gmin[t2][r];
      float thr = __uint_as_float((unsigned)(gmin[t2][r] >> 32)) + WINDOW;
      float d1f = __uint_as_float(pk1[t2][r] & MASKQ);
      float d2f = __uint_as_float(pk2[t2][r] & MASKQ);   // 0xFFFFFFE0 -> NaN: safely false
      bool in1 = d1f <= thr;
      bool in2 = d2f <= thr;
      if (in1) { int p = atomicAdd(&ccnt[row], 1); if (p < 4) cand[row][p] = (unsigned short)(((pk1[t2][r] & 31u) << 4) | res); }
      if (in2) { int p = atomicAdd(&ccnt[row], 1); if (p < 4) cand[row][p] = (unsigned short)(512 + res); }
    }
  __syncthreads();   // barrier #4: collection visible

  // ---- owner decision (every lane owns its row); x reloaded (L3-hot) ----
  int kwin;
  float xr[64];
#pragma unroll
  for (int i = 0; i < 64; i++) xr[i] = px[(size_t)i * LL];
  {
    int row = wv * 64 + lane;
    int cnt = ccnt[row];
    if (cnt <= 1) {
      kwin = (int)(g_lds[row] & 0x1FFu);
    } else {
      // exact rescue: bit-identical chains to reference
      float s;
      {
        float r[8];
#pragma unroll
        for (int j = 0; j < 8; j++) r[j] = xr[j] * xr[j];
#pragma unroll
        for (int blk = 8; blk < 64; blk += 8)
#pragma unroll
          for (int j = 0; j < 8; j++) { float a = xr[blk + j] * xr[blk + j]; r[j] = r[j] + a; }
        s = ((r[0] + r[1]) + (r[2] + r[3])) + ((r[4] + r[5]) + (r[6] + r[7]));
      }
      u64 best = ~0ULL;
      auto evalExact = [&](int c) {
        const float4* wr = (const float4*)(w + c * DD);
        float gg = 0.0f;
#pragma unroll
        for (int i = 0; i < 16; i++) {
          float4 wq = wr[i];
          gg = fmaf(xr[4 * i + 0], wq.x, gg); gg = fmaf(xr[4 * i + 1], wq.y, gg);
          gg = fmaf(xr[4 * i + 2], wq.z, gg); gg = fmaf(xr[4 * i + 3], wq.w, gg);
        }
        float de = fmaf(-2.0f, gg, s + t_lds[c]);   // ref chain: fl(s+t) then fma
        u64 pk = (((u64)__float_as_uint(de)) << 32) | (u64)c;   // de>0: bit order ok
        if (pk < best) best = pk;
      };
      if (cnt > 4) {
        for (int c = 0; c < KK; c++) evalExact(c);
      } else {
        for (int i = 0; i < cnt; i++) {
          int c = cand[row][i];
          if (c < 512) evalExact(c);
          else { int c0 = c - 512; for (int jj = 0; jj < 32; jj++) evalExact(jj * 16 + c0); }
        }
      }
      kwin = (int)(best & 0x1FFu);   // masked: logic bug => wrong answer, never OOB
    }
  }

  // ---- epilogue: quantized output (transposed back), loss partial, idx, flags ----
  float ls = 0.0f;
  {
    float* o = dout + (size_t)b * DD * LL + l;
    const float4* wr = (const float4*)(w + kwin * DD);
#pragma unroll
    for (int i = 0; i < 16; i++) {
      float4 v = wr[i];
      o[(size_t)(4 * i + 0) * LL] = v.x; o[(size_t)(4 * i + 1) * LL] = v.y;
      o[(size_t)(4 * i + 2) * LL] = v.z; o[(size_t)(4 * i + 3) * LL] = v.w;
      float df;
      df = v.x - xr[4 * i + 0]; ls = fmaf(df, df, ls);
      df = v.y - xr[4 * i + 1]; ls = fmaf(df, df, ls);
      df = v.z - xr[4 * i + 2]; ls = fmaf(df, df, ls);
      df = v.w - xr[4 * i + 3]; ls = fmaf(df, df, ls);
    }
  }
  dout[IDX_OFF + n] = (float)kwin;
  flags[kwin] = 1;   // byte races benign (same value)

  // loss: wave reduce then one atomic per wave (order-insensitive at tolerance)
#pragma unroll
  for (int o = 32; o > 0; o >>= 1) ls += __shfl_down(ls, o);
  if ((tid & 63) == 0) atomicAdd(lacc, ls);

  __syncthreads();   // barrier #5: flags complete
  for (int e = tid; e < KK; e += 256)
    if (flags[e]) atomicOr(&hist[e], 1);

  // ---- merged final: last block computes perplexity + loss scalars ----
  __threadfence();   // this block's hist/lacc atomics globally visible
  if (tid == 0) {
    int old = atomicAdd(ctr, 1);
    lastblk = (old == (int)gridDim.x - 1) ? 1 : 0;
  }
  __syncthreads();
  if (lastblk) {
    // atomic RMW reads: coherent across XCDs
    int c0 = (atomicOr(&hist[tid], 0) != 0) ? 1 : 0;
    int c1 = (atomicOr(&hist[tid + 256], 0) != 0) ? 1 : 0;
    ccnt[tid] = c0 + c1;
    __syncthreads();
    for (int sx = 128; sx > 0; sx >>= 1) {
      if (tid < sx) ccnt[tid] += ccnt[tid + sx];
      __syncthreads();
    }
    if (tid == 0) {
      dout[PERP_OFF] = (float)ccnt[0];
      float m = atomicAdd(lacc, 0.0f) / 16777216.0f;
      dout[LOSS_OFF] = m + 0.1f * m;   // q + 0.1*e with q==e numerically
    }
  }
}

extern "C" void kernel_launch(void* const* d_in, const int* in_sizes, int n_in,
                              void* d_out, int out_size, void* d_ws, size_t ws_size,
                              hipStream_t stream) {
  const float* x = (const float*)d_in[0];
  const float* w = (const float*)d_in[1];
  float* dout = (float*)d_out;
  float* ws = (float*)d_ws;

  vq_init<<<128, 256, 0, stream>>>(w, ws, dout);
  vq_main<<<NN / 256, 256, 0, stream>>>(x, w, ws, dout);
}